// Round 15
// baseline (180.133 us; speedup 1.0000x reference)
//
#include <hip/hip_runtime.h>
#include <hip/hip_bf16.h>

using bf16x8 = __attribute__((ext_vector_type(8))) short;
using f32x4  = __attribute__((ext_vector_type(4))) float;

#define MFMA_BF16(a, b, c) __builtin_amdgcn_mfma_f32_16x16x32_bf16((a), (b), (c), 0, 0, 0)

__device__ __forceinline__ unsigned short f2bf(float x) {
  union { float f; unsigned int u; } v; v.f = x;
  unsigned int r = v.u + 0x7fffu + ((v.u >> 16) & 1u);
  return (unsigned short)(r >> 16);
}

__device__ __forceinline__ unsigned int cvtpk(float a, float b) {
  __hip_bfloat162 h = __float22bfloat162_rn(make_float2(a, b));
  unsigned int u; __builtin_memcpy(&u, &h, 4); return u;
}

// truncate-pack two f32 -> bf16x2 (low = a). P>0 and the ones-MFMA denominator
// sums the same truncated values, so the bias cancels in the softmax ratio.
__device__ __forceinline__ unsigned int pack_trunc(float a, float b) {
  unsigned int ua, ub;
  __builtin_memcpy(&ua, &a, 4);
  __builtin_memcpy(&ub, &b, 4);
  return (ua >> 16) | (ub & 0xFFFF0000u);
}

// raw v_exp_f32 (no OCML range-fixup; exp2(-1e30)=0 natively)
__device__ __forceinline__ float fast_exp2(float x) {
#if __has_builtin(__builtin_amdgcn_exp2f)
  return __builtin_amdgcn_exp2f(x);
#else
  return exp2f(x);
#endif
}

__device__ __forceinline__ void gload16(const void* g, void* l) {
  __builtin_amdgcn_global_load_lds(
      (const __attribute__((address_space(1))) unsigned int*)g,
      (__attribute__((address_space(3))) unsigned int*)l, 16, 0, 0);
}

__device__ __forceinline__ void wait_and_barrier() {
  asm volatile("s_waitcnt vmcnt(0)" ::: "memory");
  __builtin_amdgcn_sched_barrier(0);
  __builtin_amdgcn_s_barrier();
  __builtin_amdgcn_sched_barrier(0);
}

// ---------------- f32 -> bf16 convert (all 5 inputs) + RoPE table, one launch ----------------
__global__ __launch_bounds__(256) void cvt_all(const float* __restrict__ x,
                                               const float* __restrict__ qw,
                                               const float* __restrict__ kw,
                                               const float* __restrict__ vw,
                                               const float* __restrict__ ow,
                                               unsigned short* __restrict__ out,
                                               const int* __restrict__ pos,
                                               float2* __restrict__ tab) {
  const int bid = blockIdx.x;
  if (bid >= 12288) {  // RoPE table segment: rows (bid-12288)*8 .. +7
    const int row = (bid - 12288) * 8 + (threadIdx.x >> 5);
    const int i = threadIdx.x & 31;
    const float p = (float)pos[row];
    const float invf = exp2f((float)(2 * i) * (-13.287712379549609f / 64.0f));
    float sn, cs;
    sincosf(p * invf, &sn, &cs);
    tab[(size_t)row * 32 + i] = make_float2(cs, sn);
    return;
  }
  int seg, loc;
  if (bid < 8192) { seg = 0; loc = bid; }
  else { seg = 1 + ((bid - 8192) >> 10); loc = (bid - 8192) & 1023; }
  const float* srcs[5] = {x, qw, kw, vw, ow};
  const float* in = srcs[seg];
  const size_t obase = (seg == 0) ? 0 : ((size_t)8192 + (size_t)(seg - 1) * 1024) * 1024;
  const int i = loc * 1024 + threadIdx.x * 4;
  float4 f = *(const float4*)(in + i);
  ushort4 o;
  o.x = f2bf(f.x); o.y = f2bf(f.y); o.z = f2bf(f.z); o.w = f2bf(f.w);
  *(ushort4*)(out + obase + i) = o;
}

// ---------------- BT-GEMM: C[m][n] = sum_k A[m][k] * Bw[n][k] ----------------
// M=8192, N=K=1024 baked. 64x128 block tile, grid 1024 (4/CU). Bijective XCD
// remap (same-A-panel blocks -> same XCD L2). BK=32 dbuf global_load_lds
// staging, one barrier per K-step (rounds 7-14 proven protocol).
// MODE 0: RoPE epilogue via table (x oscale), bf16 out [BH,S,DK]
// MODE 1: bf16 out transposed [BH,DK,S]     (V)
// MODE 2: f32 out [M,1024]                  (final projection)
template <int MODE>
__global__ __launch_bounds__(256) void gemm_bt(const unsigned short* __restrict__ A,
                                               const unsigned short* __restrict__ Bw,
                                               void* __restrict__ outp,
                                               const float2* __restrict__ tab,
                                               float oscale) {
  constexpr int K = 1024;
  __shared__ __align__(16) unsigned short smem[12288];
  const int tid  = threadIdx.x;
  const int lane = tid & 63, wave = tid >> 6;
  const int wr = wave >> 1, wc = wave & 1;
  const int bid = blockIdx.x + (blockIdx.y << 3);
  const int xcd = bid & 7;
  const int t6  = bid >> 3;
  const int bn0 = (t6 & 7) * 128;
  const int bm0 = (((t6 >> 3) << 3) + xcd) * 64;
  const int lrow = lane & 15, hi = lane >> 4, lko = hi * 8;
  const int srow = tid >> 2, scol = (tid & 3) * 8;
  const unsigned short* gA = A + (size_t)(bm0 + srow) * K + scol;
  const unsigned short* gB = Bw + (size_t)(bn0 + srow) * K + scol;
  const f32x4 z = {0.f, 0.f, 0.f, 0.f};
  f32x4 acc[2][4];
#pragma unroll
  for (int i = 0; i < 2; ++i)
#pragma unroll
    for (int j = 0; j < 4; ++j) acc[i][j] = z;

  auto stage = [&](int k0, int c) {
    char* base = (char*)smem + c * 12288;
    gload16(gA + k0, base + wave * 1024);
    gload16(gB + k0, base + 4096 + wave * 1024);
    gload16(gB + k0 + (size_t)64 * K, base + 8192 + wave * 1024);
  };

  stage(0, 0);
  int cur = 0;
#pragma unroll 1
  for (int k0 = 0; k0 < K; k0 += 32) {
    wait_and_barrier();
    if (k0 + 32 < K) stage(k0 + 32, cur ^ 1);
    const int ub = cur * 6144;
    bf16x8 af[2], bfr[4];
#pragma unroll
    for (int mi = 0; mi < 2; ++mi)
      af[mi] = *(const bf16x8*)&smem[ub + (wr * 32 + mi * 16 + lrow) * 32 + lko];
#pragma unroll
    for (int ni = 0; ni < 4; ++ni)
      bfr[ni] = *(const bf16x8*)&smem[ub + 2048 + (wc * 64 + ni * 16 + lrow) * 32 + lko];
#pragma unroll
    for (int mi = 0; mi < 2; ++mi)
#pragma unroll
      for (int ni = 0; ni < 4; ++ni)
        acc[mi][ni] = MFMA_BF16(af[mi], bfr[ni], acc[mi][ni]);
    cur ^= 1;
  }

  if (MODE == 2) {
#pragma unroll
    for (int mi = 0; mi < 2; ++mi)
#pragma unroll
      for (int r = 0; r < 4; ++r) {
        const int row = bm0 + wr * 32 + mi * 16 + hi * 4 + r;
#pragma unroll
        for (int ni = 0; ni < 4; ++ni) {
          const int col = bn0 + wc * 64 + ni * 16 + lrow;
          ((float*)outp)[(size_t)row * 1024 + col] = acc[mi][ni][r];
        }
      }
    return;
  }

  const int h0 = bn0 >> 6;
  const int bb = bm0 >> 11, s0 = bm0 & 2047;
  unsigned short* dst = (unsigned short*)outp;
  __syncthreads();  // all waves done reading staging; reuse smem as C-tile
  if (MODE == 0) {
#pragma unroll
    for (int mi = 0; mi < 2; ++mi)
#pragma unroll
      for (int ni = 0; ni < 4; ++ni) {
        const int col = wc * 64 + ni * 16 + lrow;
        const int d = col & 63;
#pragma unroll
        for (int r = 0; r < 4; ++r) {
          const int row = wr * 32 + mi * 16 + hi * 4 + r;
          const float2 t = tab[(size_t)(bm0 + row) * 32 + (d >> 1)];
          const float v = acc[mi][ni][r];
          const float other = __shfl_xor(v, 1);
          const float rv = (d & 1) ? (other * t.y + v * t.x) : (v * t.x - other * t.y);
          smem[row * 136 + col] = f2bf(rv * oscale);
        }
      }
    __syncthreads();
#pragma unroll
    for (int it = 0; it < 4; ++it) {
      const int c = it * 256 + tid;
      const int hl = c >> 9, rem = c & 511;
      const int sl = rem >> 3, ch = (rem & 7) * 8;
      const bf16x8 val = *(const bf16x8*)&smem[sl * 136 + hl * 64 + ch];
      *(bf16x8*)&dst[((size_t)(bb * 16 + h0 + hl) * 2048 + s0 + sl) * 64 + ch] = val;
    }
  } else {
#pragma unroll
    for (int mi = 0; mi < 2; ++mi)
#pragma unroll
      for (int ni = 0; ni < 4; ++ni) {
        const int col = wc * 64 + ni * 16 + lrow;
        ushort4 pk;
        pk.x = f2bf(acc[mi][ni][0]); pk.y = f2bf(acc[mi][ni][1]);
        pk.z = f2bf(acc[mi][ni][2]); pk.w = f2bf(acc[mi][ni][3]);
        *(ushort4*)&smem[col * 72 + wr * 32 + mi * 16 + hi * 4] = pk;
      }
    __syncthreads();
#pragma unroll
    for (int it = 0; it < 4; ++it) {
      const int c = it * 256 + tid;
      const int cl = c >> 3, sc = (c & 7) * 8;
      const bf16x8 val = *(const bf16x8*)&smem[cl * 72 + sc];
      *(bf16x8*)&dst[((size_t)(bb * 16 + h0 + (cl >> 6)) * 64 + (cl & 63)) * 2048 + s0 + sc] = val;
    }
  }
}

// ---------------- causal flash attention (swapped QK^T, no-max softmax) ----------------
// QBLK=128, 2 q-chains/wave, K/V frags shared between chains. Grid 1024: one
// q-block per block, 4 blocks/CU (LDS 40KB x4 = 160KB exactly). Static balance
// via qmap: under round-robin dispatch each CU's 4 resident blocks sum to 34
// tiles. bh in low 6 bits keeps XCD = bh%8 (8 heads/XCD L2 locality). Sync
// protocol unchanged from rounds 9-14: {sync, stage128, sync, compute}.
__global__ __launch_bounds__(256) void attn_fwd(const unsigned short* __restrict__ Q,
                                                const unsigned short* __restrict__ Kk,
                                                const unsigned short* __restrict__ Vt,
                                                unsigned short* __restrict__ O) {
  __shared__ __align__(16) unsigned short Ks[8192];     // [128 kv][64 d] swizzled
  __shared__ __align__(16) unsigned short Vs[8192];     // [64 d][128 kv] swizzled
  __shared__ __align__(16) unsigned short Plds[4][16][64];  // chunk-XOR swizzled
  const int p = blockIdx.x;
  const int bh = p & 63;
  // per-CU balanced q-block map: 4-subsets {16,12,5,1},{15,11,6,2},{14,10,7,3},{13,9,8,4}
  const int qmap[16] = {15, 14, 13, 12, 11, 10, 9, 8, 4, 5, 6, 7, 0, 1, 2, 3};
  const int qb = qmap[p >> 6];
  const int tid = threadIdx.x;
  const int lane = tid & 63, wave = tid >> 6;
  const int lrow = lane & 15, hi = lane >> 4;
  const int l7 = lrow & 7;
  const unsigned short* Qb = Q + (size_t)bh * 2048 * 64;
  const unsigned short* Kb = Kk + (size_t)bh * 2048 * 64;
  const unsigned short* Vb = Vt + (size_t)bh * 64 * 2048;
  const int rK   = tid >> 3;                              // +32/pass
  const int colK = ((tid & 7) ^ ((tid >> 3) & 7)) * 8;
  const int rV   = tid >> 4;
  const int colV = ((tid & 8) | ((tid & 7) ^ ((tid >> 4) & 7))) * 8;
  const int b = bh >> 4, h = bh & 15;
  const f32x4 z = {0.f, 0.f, 0.f, 0.f};
  const short one = (short)0x3F80;  // bf16 1.0
  const bf16x8 ones = {one, one, one, one, one, one, one, one};
  const int qrl = wave * 16 + lrow;   // local q row within a chain (0..63)

  auto stage128 = [&](int kv0) {
#pragma unroll
    for (int pass = 0; pass < 4; ++pass)
      gload16(Kb + (size_t)(kv0 + rK + 32 * pass) * 64 + colK,
              (char*)Ks + pass * 4096 + wave * 1024);
#pragma unroll
    for (int pass = 0; pass < 4; ++pass)
      gload16(Vb + (size_t)(rV + 16 * pass) * 2048 + kv0 + colV,
              (char*)Vs + pass * 4096 + wave * 1024);
  };

  const int qga = qb * 128 + qrl;         // chain a global q row
  const int qgb = qga + 64;               // chain b global q row
  const bf16x8 qfa0 = *(const bf16x8*)(Qb + (size_t)qga * 64 + hi * 8);
  const bf16x8 qfa1 = *(const bf16x8*)(Qb + (size_t)qga * 64 + 32 + hi * 8);
  const bf16x8 qfb0 = *(const bf16x8*)(Qb + (size_t)qgb * 64 + hi * 8);
  const bf16x8 qfb1 = *(const bf16x8*)(Qb + (size_t)qgb * 64 + 32 + hi * 8);
  f32x4 acca[4] = {z, z, z, z}, accb[4] = {z, z, z, z};
  f32x4 acc_la = z, acc_lb = z;

  // softmax + PV for one chain on one 64-kv half (st consumed; vf shared)
  auto sm_pv = [&](f32x4* st, const bf16x8* vf, f32x4* acc, f32x4& acc_l,
                   bool dg) {
    if (dg) {
#pragma unroll
      for (int n = 0; n < 4; ++n)
#pragma unroll
        for (int r = 0; r < 4; ++r)
          if (n * 16 + hi * 4 + r > qrl) st[n][r] = -1e30f;
    }
    float pe[16];
#pragma unroll
    for (int n = 0; n < 4; ++n)
#pragma unroll
      for (int r = 0; r < 4; ++r) pe[n * 4 + r] = fast_exp2(st[n][r]);
#pragma unroll
    for (int n = 0; n < 4; ++n) {
      uint2 pk;
      pk.x = pack_trunc(pe[n * 4 + 0], pe[n * 4 + 1]);
      pk.y = pack_trunc(pe[n * 4 + 2], pe[n * 4 + 3]);
      const int eo = ((((n * 2 + (hi >> 1)) ^ l7) << 3) | ((hi & 1) << 2));
      *(uint2*)&Plds[wave][lrow][eo] = pk;
    }
    const bf16x8 pf0 = *(const bf16x8*)&Plds[wave][lrow][(hi ^ l7) << 3];
    const bf16x8 pf1 = *(const bf16x8*)&Plds[wave][lrow][((4 + hi) ^ l7) << 3];
    acc_l = MFMA_BF16(ones, pf0, acc_l);   // row-sum on the matrix pipe
    acc_l = MFMA_BF16(ones, pf1, acc_l);
#pragma unroll
    for (int dt = 0; dt < 4; ++dt) {
      acc[dt] = MFMA_BF16(vf[dt * 2], pf0, acc[dt]);
      acc[dt] = MFMA_BF16(vf[dt * 2 + 1], pf1, acc[dt]);
    }
  };

  // one 64-kv half: K/V frags read once, feed both chains
  auto process_half = [&](const char* Kbase, const char* Vbase,
                          bool doA, bool dgA, bool dgB) {
    bf16x8 kf[8];
#pragma unroll
    for (int n = 0; n < 4; ++n) {
      const int rk = n * 16 + lrow;
      kf[n * 2]     = *(const bf16x8*)(Kbase + rk * 128 + ((hi ^ l7) * 16));
      kf[n * 2 + 1] = *(const bf16x8*)(Kbase + rk * 128 + (((4 + hi) ^ l7) * 16));
    }
    f32x4 sta[4], stb[4];
    __builtin_amdgcn_s_setprio(1);
    if (doA) {
#pragma unroll
      for (int n = 0; n < 4; ++n) {
        sta[n] = MFMA_BF16(kf[n * 2], qfa0, z);
        sta[n] = MFMA_BF16(kf[n * 2 + 1], qfa1, sta[n]);
      }
    }
#pragma unroll
    for (int n = 0; n < 4; ++n) {
      stb[n] = MFMA_BF16(kf[n * 2], qfb0, z);
      stb[n] = MFMA_BF16(kf[n * 2 + 1], qfb1, stb[n]);
    }
    __builtin_amdgcn_s_setprio(0);
    bf16x8 vf[8];
#pragma unroll
    for (int dt = 0; dt < 4; ++dt) {
      const int rv = dt * 16 + lrow;
      vf[dt * 2]     = *(const bf16x8*)(Vbase + rv * 256 + ((hi ^ l7) * 16));
      vf[dt * 2 + 1] = *(const bf16x8*)(Vbase + rv * 256 + (((4 + hi) ^ l7) * 16));
    }
    if (doA) sm_pv(sta, vf, acca, acc_la, dgA);
    sm_pv(stb, vf, accb, acc_lb, dgB);
  };

#pragma unroll 1
  for (int f = 0; f <= qb; ++f) {
    __syncthreads();                     // prev tile's LDS reads done
    stage128(f * 128);
    __syncthreads();                     // staged tile visible
    const bool dg = (f == qb);
    process_half((char*)Ks, (char*)Vs, true, dg, false);             // kv 0..63
    process_half((char*)Ks + 8192, (char*)Vs + 128, !dg, false, dg); // kv 64..127
  }

  const float inva = 1.0f / acc_la[0];
  const float invb = 1.0f / acc_lb[0];
#pragma unroll
  for (int dt = 0; dt < 4; ++dt) {
    uint2 ov;
    ov.x = cvtpk(acca[dt][0] * inva, acca[dt][1] * inva);
    ov.y = cvtpk(acca[dt][2] * inva, acca[dt][3] * inva);
    *(uint2*)&O[((size_t)b * 2048 + qga) * 1024 + h * 64 + dt * 16 + hi * 4] = ov;
    uint2 ow2;
    ow2.x = cvtpk(accb[dt][0] * invb, accb[dt][1] * invb);
    ow2.y = cvtpk(accb[dt][2] * invb, accb[dt][3] * invb);
    *(uint2*)&O[((size_t)b * 2048 + qgb) * 1024 + h * 64 + dt * 16 + hi * 4] = ow2;
  }
}

extern "C" void kernel_launch(void* const* d_in, const int* in_sizes, int n_in,
                              void* d_out, int out_size, void* d_ws, size_t ws_size,
                              hipStream_t stream) {
  const float* x  = (const float*)d_in[0];
  const float* qw = (const float*)d_in[1];
  const float* kw = (const float*)d_in[2];
  const float* vw = (const float*)d_in[3];
  const float* ow = (const float*)d_in[4];
  const int* pos  = (const int*)d_in[5];
  float* out = (float*)d_out;

  unsigned short* xb  = (unsigned short*)d_ws;            // [8192,1024]
  unsigned short* qwb = xb  + (size_t)8192 * 1024;        // [1024,1024] x4
  unsigned short* kwb = qwb + (size_t)1024 * 1024;
  unsigned short* vwb = kwb + (size_t)1024 * 1024;
  unsigned short* owb = vwb + (size_t)1024 * 1024;
  unsigned short* Qr  = owb + (size_t)1024 * 1024;        // [BH,S,DK], pre-scaled
  unsigned short* Kr  = Qr  + (size_t)8192 * 1024;        // [BH,S,DK]
  unsigned short* Vtr = Kr  + (size_t)8192 * 1024;        // [BH,DK,S]
  unsigned short* AO  = Vtr + (size_t)8192 * 1024;        // [8192,1024]
  float2* tab = (float2*)(AO + (size_t)8192 * 1024);      // [8192][32] cos/sin

  cvt_all<<<13312, 256, 0, stream>>>(x, qw, kw, vw, ow, xb, pos, tab);

  constexpr float SCALE = 0.18033688011112042f;  // 0.125 * log2(e)
  dim3 gg(8, 128);  // (1024/128, 8192/64)
  gemm_bt<0><<<gg, 256, 0, stream>>>(xb, qwb, Qr,  tab, SCALE);
  gemm_bt<0><<<gg, 256, 0, stream>>>(xb, kwb, Kr,  tab, 1.0f);
  gemm_bt<1><<<gg, 256, 0, stream>>>(xb, vwb, Vtr, nullptr, 1.0f);
  attn_fwd<<<1024, 256, 0, stream>>>(Qr, Kr, Vtr, AO);
  gemm_bt<2><<<gg, 256, 0, stream>>>(AO, owb, out, nullptr, 1.0f);
}

// Round 16
// 173.753 us; speedup vs baseline: 1.0367x; 1.0367x over previous
//
#include <hip/hip_runtime.h>
#include <hip/hip_bf16.h>

using bf16x8 = __attribute__((ext_vector_type(8))) short;
using f32x4  = __attribute__((ext_vector_type(4))) float;

#define MFMA_BF16(a, b, c) __builtin_amdgcn_mfma_f32_16x16x32_bf16((a), (b), (c), 0, 0, 0)

__device__ __forceinline__ unsigned short f2bf(float x) {
  union { float f; unsigned int u; } v; v.f = x;
  unsigned int r = v.u + 0x7fffu + ((v.u >> 16) & 1u);
  return (unsigned short)(r >> 16);
}

__device__ __forceinline__ unsigned int cvtpk(float a, float b) {
  __hip_bfloat162 h = __float22bfloat162_rn(make_float2(a, b));
  unsigned int u; __builtin_memcpy(&u, &h, 4); return u;
}

// truncate-pack two f32 -> bf16x2 (low = a). P>0 and the ones-MFMA denominator
// sums the same truncated values, so the bias cancels in the softmax ratio.
__device__ __forceinline__ unsigned int pack_trunc(float a, float b) {
  unsigned int ua, ub;
  __builtin_memcpy(&ua, &a, 4);
  __builtin_memcpy(&ub, &b, 4);
  return (ua >> 16) | (ub & 0xFFFF0000u);
}

// raw v_exp_f32 (no OCML range-fixup; exp2(-1e30)=0 natively)
__device__ __forceinline__ float fast_exp2(float x) {
#if __has_builtin(__builtin_amdgcn_exp2f)
  return __builtin_amdgcn_exp2f(x);
#else
  return exp2f(x);
#endif
}

__device__ __forceinline__ void gload16(const void* g, void* l) {
  __builtin_amdgcn_global_load_lds(
      (const __attribute__((address_space(1))) unsigned int*)g,
      (__attribute__((address_space(3))) unsigned int*)l, 16, 0, 0);
}

__device__ __forceinline__ void wait_and_barrier() {
  asm volatile("s_waitcnt vmcnt(0)" ::: "memory");
  __builtin_amdgcn_sched_barrier(0);
  __builtin_amdgcn_s_barrier();
  __builtin_amdgcn_sched_barrier(0);
}

// ---------------- f32 -> bf16 convert (all 5 inputs) + RoPE table, one launch ----------------
// 8 f32/thread (2x float4 in, 1x 16B out). Segments: x 4096 blocks, weights
// 4x512, tab 1024. Total 7168 blocks.
__global__ __launch_bounds__(256) void cvt_all(const float* __restrict__ x,
                                               const float* __restrict__ qw,
                                               const float* __restrict__ kw,
                                               const float* __restrict__ vw,
                                               const float* __restrict__ ow,
                                               unsigned short* __restrict__ out,
                                               const int* __restrict__ pos,
                                               float2* __restrict__ tab) {
  const int bid = blockIdx.x;
  if (bid >= 6144) {  // RoPE table segment: rows (bid-6144)*8 .. +7
    const int row = (bid - 6144) * 8 + (threadIdx.x >> 5);
    const int i = threadIdx.x & 31;
    const float p = (float)pos[row];
    const float invf = exp2f((float)(2 * i) * (-13.287712379549609f / 64.0f));
    float sn, cs;
    sincosf(p * invf, &sn, &cs);
    tab[(size_t)row * 32 + i] = make_float2(cs, sn);
    return;
  }
  int seg, loc;
  if (bid < 4096) { seg = 0; loc = bid; }
  else { seg = 1 + ((bid - 4096) >> 9); loc = (bid - 4096) & 511; }
  const float* srcs[5] = {x, qw, kw, vw, ow};
  const float* in = srcs[seg];
  const size_t obase = (seg == 0) ? 0 : ((size_t)8192 + (size_t)(seg - 1) * 1024) * 1024;
  const int i = loc * 2048 + threadIdx.x * 8;
  float4 f0 = *(const float4*)(in + i);
  float4 f1 = *(const float4*)(in + i + 4);
  bf16x8 o;
  o[0] = (short)f2bf(f0.x); o[1] = (short)f2bf(f0.y);
  o[2] = (short)f2bf(f0.z); o[3] = (short)f2bf(f0.w);
  o[4] = (short)f2bf(f1.x); o[5] = (short)f2bf(f1.y);
  o[6] = (short)f2bf(f1.z); o[7] = (short)f2bf(f1.w);
  *(bf16x8*)(out + obase + i) = o;
}

// ---------------- fused QKV BT-GEMM ----------------
// grid (8,128,3): z selects proj (0=Q RoPE+scale, 1=K RoPE, 2=V transposed).
// Same 64x128 tile / BK=32 dbuf global_load_lds / one barrier per K-step as
// the proven gemm_bt. Epilogue branch is block-uniform (z).
__global__ __launch_bounds__(256) void gemm_qkv(const unsigned short* __restrict__ A,
                                                const unsigned short* __restrict__ W,
                                                unsigned short* __restrict__ Qr,
                                                const float2* __restrict__ tab) {
  constexpr int K = 1024;
  constexpr float SCALE = 0.18033688011112042f;  // 0.125 * log2(e)
  __shared__ __align__(16) unsigned short smem[12288];
  const int tid  = threadIdx.x;
  const int lane = tid & 63, wave = tid >> 6;
  const int wr = wave >> 1, wc = wave & 1;
  const int z = blockIdx.z;
  const unsigned short* Bw = W + (size_t)z * 1048576;
  const int bid = blockIdx.x + (blockIdx.y << 3);
  const int xcd = bid & 7;
  const int t6  = bid >> 3;
  const int bn0 = (t6 & 7) * 128;
  const int bm0 = (((t6 >> 3) << 3) + xcd) * 64;
  const int lrow = lane & 15, hi = lane >> 4, lko = hi * 8;
  const int srow = tid >> 2, scol = (tid & 3) * 8;
  const unsigned short* gA = A + (size_t)(bm0 + srow) * K + scol;
  const unsigned short* gB = Bw + (size_t)(bn0 + srow) * K + scol;
  const f32x4 z4 = {0.f, 0.f, 0.f, 0.f};
  f32x4 acc[2][4];
#pragma unroll
  for (int i = 0; i < 2; ++i)
#pragma unroll
    for (int j = 0; j < 4; ++j) acc[i][j] = z4;

  auto stage = [&](int k0, int c) {
    char* base = (char*)smem + c * 12288;
    gload16(gA + k0, base + wave * 1024);
    gload16(gB + k0, base + 4096 + wave * 1024);
    gload16(gB + k0 + (size_t)64 * K, base + 8192 + wave * 1024);
  };

  stage(0, 0);
  int cur = 0;
#pragma unroll 1
  for (int k0 = 0; k0 < K; k0 += 32) {
    wait_and_barrier();
    if (k0 + 32 < K) stage(k0 + 32, cur ^ 1);
    const int ub = cur * 6144;
    bf16x8 af[2], bfr[4];
#pragma unroll
    for (int mi = 0; mi < 2; ++mi)
      af[mi] = *(const bf16x8*)&smem[ub + (wr * 32 + mi * 16 + lrow) * 32 + lko];
#pragma unroll
    for (int ni = 0; ni < 4; ++ni)
      bfr[ni] = *(const bf16x8*)&smem[ub + 2048 + (wc * 64 + ni * 16 + lrow) * 32 + lko];
#pragma unroll
    for (int mi = 0; mi < 2; ++mi)
#pragma unroll
      for (int ni = 0; ni < 4; ++ni)
        acc[mi][ni] = MFMA_BF16(af[mi], bfr[ni], acc[mi][ni]);
    cur ^= 1;
  }

  const int h0 = bn0 >> 6;
  const int bb = bm0 >> 11, s0 = bm0 & 2047;
  unsigned short* dst = (z == 0) ? Qr : (z == 1 ? Qr + (size_t)8388608
                                               : Qr + (size_t)16777216);
  const float oscale = (z == 0) ? SCALE : 1.0f;
  __syncthreads();  // all waves done reading staging; reuse smem as C-tile
  if (z < 2) {
    // RoPE in registers (pair partner in lane^1), C-tile [64 s][136 pad]
#pragma unroll
    for (int mi = 0; mi < 2; ++mi)
#pragma unroll
      for (int ni = 0; ni < 4; ++ni) {
        const int col = wc * 64 + ni * 16 + lrow;
        const int d = col & 63;
#pragma unroll
        for (int r = 0; r < 4; ++r) {
          const int row = wr * 32 + mi * 16 + hi * 4 + r;
          const float2 t = tab[(size_t)(bm0 + row) * 32 + (d >> 1)];
          const float v = acc[mi][ni][r];
          const float other = __shfl_xor(v, 1);
          const float rv = (d & 1) ? (other * t.y + v * t.x) : (v * t.x - other * t.y);
          smem[row * 136 + col] = f2bf(rv * oscale);
        }
      }
    __syncthreads();
#pragma unroll
    for (int it = 0; it < 4; ++it) {
      const int c = it * 256 + tid;
      const int hl = c >> 9, rem = c & 511;
      const int sl = rem >> 3, ch = (rem & 7) * 8;
      const bf16x8 val = *(const bf16x8*)&smem[sl * 136 + hl * 64 + ch];
      *(bf16x8*)&dst[((size_t)(bb * 16 + h0 + hl) * 2048 + s0 + sl) * 64 + ch] = val;
    }
  } else {
    // V: C^T tile [128 c][72 pad s] (transpose at LDS-write, packed r-quad)
#pragma unroll
    for (int mi = 0; mi < 2; ++mi)
#pragma unroll
      for (int ni = 0; ni < 4; ++ni) {
        const int col = wc * 64 + ni * 16 + lrow;
        ushort4 pk;
        pk.x = f2bf(acc[mi][ni][0]); pk.y = f2bf(acc[mi][ni][1]);
        pk.z = f2bf(acc[mi][ni][2]); pk.w = f2bf(acc[mi][ni][3]);
        *(ushort4*)&smem[col * 72 + wr * 32 + mi * 16 + hi * 4] = pk;
      }
    __syncthreads();
#pragma unroll
    for (int it = 0; it < 4; ++it) {
      const int c = it * 256 + tid;
      const int cl = c >> 3, sc = (c & 7) * 8;
      const bf16x8 val = *(const bf16x8*)&smem[cl * 72 + sc];
      *(bf16x8*)&dst[((size_t)(bb * 16 + h0 + (cl >> 6)) * 64 + (cl & 63)) * 2048 + s0 + sc] = val;
    }
  }
}

// ---------------- O-projection BT-GEMM (f32 out) ----------------
__global__ __launch_bounds__(256) void gemm_o(const unsigned short* __restrict__ A,
                                              const unsigned short* __restrict__ Bw,
                                              float* __restrict__ outp) {
  constexpr int K = 1024;
  __shared__ __align__(16) unsigned short smem[12288];
  const int tid  = threadIdx.x;
  const int lane = tid & 63, wave = tid >> 6;
  const int wr = wave >> 1, wc = wave & 1;
  const int bid = blockIdx.x + (blockIdx.y << 3);
  const int xcd = bid & 7;
  const int t6  = bid >> 3;
  const int bn0 = (t6 & 7) * 128;
  const int bm0 = (((t6 >> 3) << 3) + xcd) * 64;
  const int lrow = lane & 15, hi = lane >> 4, lko = hi * 8;
  const int srow = tid >> 2, scol = (tid & 3) * 8;
  const unsigned short* gA = A + (size_t)(bm0 + srow) * K + scol;
  const unsigned short* gB = Bw + (size_t)(bn0 + srow) * K + scol;
  const f32x4 z = {0.f, 0.f, 0.f, 0.f};
  f32x4 acc[2][4];
#pragma unroll
  for (int i = 0; i < 2; ++i)
#pragma unroll
    for (int j = 0; j < 4; ++j) acc[i][j] = z;

  auto stage = [&](int k0, int c) {
    char* base = (char*)smem + c * 12288;
    gload16(gA + k0, base + wave * 1024);
    gload16(gB + k0, base + 4096 + wave * 1024);
    gload16(gB + k0 + (size_t)64 * K, base + 8192 + wave * 1024);
  };

  stage(0, 0);
  int cur = 0;
#pragma unroll 1
  for (int k0 = 0; k0 < K; k0 += 32) {
    wait_and_barrier();
    if (k0 + 32 < K) stage(k0 + 32, cur ^ 1);
    const int ub = cur * 6144;
    bf16x8 af[2], bfr[4];
#pragma unroll
    for (int mi = 0; mi < 2; ++mi)
      af[mi] = *(const bf16x8*)&smem[ub + (wr * 32 + mi * 16 + lrow) * 32 + lko];
#pragma unroll
    for (int ni = 0; ni < 4; ++ni)
      bfr[ni] = *(const bf16x8*)&smem[ub + 2048 + (wc * 64 + ni * 16 + lrow) * 32 + lko];
#pragma unroll
    for (int mi = 0; mi < 2; ++mi)
#pragma unroll
      for (int ni = 0; ni < 4; ++ni)
        acc[mi][ni] = MFMA_BF16(af[mi], bfr[ni], acc[mi][ni]);
    cur ^= 1;
  }

#pragma unroll
  for (int mi = 0; mi < 2; ++mi)
#pragma unroll
    for (int r = 0; r < 4; ++r) {
      const int row = bm0 + wr * 32 + mi * 16 + hi * 4 + r;
#pragma unroll
      for (int ni = 0; ni < 4; ++ni) {
        const int col = bn0 + wc * 64 + ni * 16 + lrow;
        outp[(size_t)row * 1024 + col] = acc[mi][ni][r];
      }
    }
}

// ---------------- causal flash attention (swapped QK^T, no-max softmax) ----------------
// ROUND-14 PROVEN VERSION (62 us): QBLK=128, 2 q-chains/wave, K/V frags shared
// between chains, grid 512 with complementary pairing (qb <-> 15-qb, 17 tiles
// per block, perfectly balanced). Sync protocol: {sync, stage128, sync,
// compute} per 128-row KV tile. Round-15's qmap/grid-1024 regressed — reverted.
__global__ __launch_bounds__(256) void attn_fwd(const unsigned short* __restrict__ Q,
                                                const unsigned short* __restrict__ Kk,
                                                const unsigned short* __restrict__ Vt,
                                                unsigned short* __restrict__ O) {
  __shared__ __align__(16) unsigned short Ks[8192];     // [128 kv][64 d] swizzled
  __shared__ __align__(16) unsigned short Vs[8192];     // [64 d][128 kv] swizzled
  __shared__ __align__(16) unsigned short Plds[4][16][64];  // chunk-XOR swizzled
  const int p = blockIdx.x;
  const int L = (p & 7) * 64 + (p >> 3);  // XCD swizzle: 8 heads/XCD (4MB K/V = L2)
  const int bh = L >> 3, pr = L & 7;
  const int tid = threadIdx.x;
  const int lane = tid & 63, wave = tid >> 6;
  const int lrow = lane & 15, hi = lane >> 4;
  const int l7 = lrow & 7;
  const unsigned short* Qb = Q + (size_t)bh * 2048 * 64;
  const unsigned short* Kb = Kk + (size_t)bh * 2048 * 64;
  const unsigned short* Vb = Vt + (size_t)bh * 64 * 2048;
  const int rK   = tid >> 3;                              // +32/pass
  const int colK = ((tid & 7) ^ ((tid >> 3) & 7)) * 8;
  const int rV   = tid >> 4;
  const int colV = ((tid & 8) | ((tid & 7) ^ ((tid >> 4) & 7))) * 8;
  const int b = bh >> 4, h = bh & 15;
  const f32x4 z = {0.f, 0.f, 0.f, 0.f};
  const short one = (short)0x3F80;  // bf16 1.0
  const bf16x8 ones = {one, one, one, one, one, one, one, one};
  const int qrl = wave * 16 + lrow;   // local q row within a chain (0..63)

  auto stage128 = [&](int kv0) {
#pragma unroll
    for (int pass = 0; pass < 4; ++pass)
      gload16(Kb + (size_t)(kv0 + rK + 32 * pass) * 64 + colK,
              (char*)Ks + pass * 4096 + wave * 1024);
#pragma unroll
    for (int pass = 0; pass < 4; ++pass)
      gload16(Vb + (size_t)(rV + 16 * pass) * 2048 + kv0 + colV,
              (char*)Vs + pass * 4096 + wave * 1024);
  };

  for (int half = 0; half < 2; ++half) {
    const int qb = half ? (15 - pr) : pr;   // 128-row q block index
    const int qga = qb * 128 + qrl;         // chain a global q row
    const int qgb = qga + 64;               // chain b global q row
    const bf16x8 qfa0 = *(const bf16x8*)(Qb + (size_t)qga * 64 + hi * 8);
    const bf16x8 qfa1 = *(const bf16x8*)(Qb + (size_t)qga * 64 + 32 + hi * 8);
    const bf16x8 qfb0 = *(const bf16x8*)(Qb + (size_t)qgb * 64 + hi * 8);
    const bf16x8 qfb1 = *(const bf16x8*)(Qb + (size_t)qgb * 64 + 32 + hi * 8);
    f32x4 acca[4] = {z, z, z, z}, accb[4] = {z, z, z, z};
    f32x4 acc_la = z, acc_lb = z;

    // softmax + PV for one chain on one 64-kv half (st consumed; vf shared)
    auto sm_pv = [&](f32x4* st, const bf16x8* vf, f32x4* acc, f32x4& acc_l,
                     bool dg) {
      if (dg) {
#pragma unroll
        for (int n = 0; n < 4; ++n)
#pragma unroll
          for (int r = 0; r < 4; ++r)
            if (n * 16 + hi * 4 + r > qrl) st[n][r] = -1e30f;
      }
      float pe[16];
#pragma unroll
      for (int n = 0; n < 4; ++n)
#pragma unroll
        for (int r = 0; r < 4; ++r) pe[n * 4 + r] = fast_exp2(st[n][r]);
#pragma unroll
      for (int n = 0; n < 4; ++n) {
        uint2 pk;
        pk.x = pack_trunc(pe[n * 4 + 0], pe[n * 4 + 1]);
        pk.y = pack_trunc(pe[n * 4 + 2], pe[n * 4 + 3]);
        const int eo = ((((n * 2 + (hi >> 1)) ^ l7) << 3) | ((hi & 1) << 2));
        *(uint2*)&Plds[wave][lrow][eo] = pk;
      }
      const bf16x8 pf0 = *(const bf16x8*)&Plds[wave][lrow][(hi ^ l7) << 3];
      const bf16x8 pf1 = *(const bf16x8*)&Plds[wave][lrow][((4 + hi) ^ l7) << 3];
      acc_l = MFMA_BF16(ones, pf0, acc_l);   // row-sum on the matrix pipe
      acc_l = MFMA_BF16(ones, pf1, acc_l);
#pragma unroll
      for (int dt = 0; dt < 4; ++dt) {
        acc[dt] = MFMA_BF16(vf[dt * 2], pf0, acc[dt]);
        acc[dt] = MFMA_BF16(vf[dt * 2 + 1], pf1, acc[dt]);
      }
    };

    // one 64-kv half: K/V frags read once, feed both chains
    auto process_half = [&](const char* Kbase, const char* Vbase,
                            bool doA, bool dgA, bool dgB) {
      bf16x8 kf[8];
#pragma unroll
      for (int n = 0; n < 4; ++n) {
        const int rk = n * 16 + lrow;
        kf[n * 2]     = *(const bf16x8*)(Kbase + rk * 128 + ((hi ^ l7) * 16));
        kf[n * 2 + 1] = *(const bf16x8*)(Kbase + rk * 128 + (((4 + hi) ^ l7) * 16));
      }
      f32x4 sta[4], stb[4];
      __builtin_amdgcn_s_setprio(1);
      if (doA) {
#pragma unroll
        for (int n = 0; n < 4; ++n) {
          sta[n] = MFMA_BF16(kf[n * 2], qfa0, z);
          sta[n] = MFMA_BF16(kf[n * 2 + 1], qfa1, sta[n]);
        }
      }
#pragma unroll
      for (int n = 0; n < 4; ++n) {
        stb[n] = MFMA_BF16(kf[n * 2], qfb0, z);
        stb[n] = MFMA_BF16(kf[n * 2 + 1], qfb1, stb[n]);
      }
      __builtin_amdgcn_s_setprio(0);
      bf16x8 vf[8];
#pragma unroll
      for (int dt = 0; dt < 4; ++dt) {
        const int rv = dt * 16 + lrow;
        vf[dt * 2]     = *(const bf16x8*)(Vbase + rv * 256 + ((hi ^ l7) * 16));
        vf[dt * 2 + 1] = *(const bf16x8*)(Vbase + rv * 256 + (((4 + hi) ^ l7) * 16));
      }
      if (doA) sm_pv(sta, vf, acca, acc_la, dgA);
      sm_pv(stb, vf, accb, acc_lb, dgB);
    };

#pragma unroll 1
    for (int f = 0; f <= qb; ++f) {
      __syncthreads();                     // prev tile's LDS reads done
      stage128(f * 128);
      __syncthreads();                     // staged tile visible
      const bool dg = (f == qb);
      process_half((char*)Ks, (char*)Vs, true, dg, false);             // kv 0..63
      process_half((char*)Ks + 8192, (char*)Vs + 128, !dg, false, dg); // kv 64..127
    }

    const float inva = 1.0f / acc_la[0];
    const float invb = 1.0f / acc_lb[0];
#pragma unroll
    for (int dt = 0; dt < 4; ++dt) {
      uint2 ov;
      ov.x = cvtpk(acca[dt][0] * inva, acca[dt][1] * inva);
      ov.y = cvtpk(acca[dt][2] * inva, acca[dt][3] * inva);
      *(uint2*)&O[((size_t)b * 2048 + qga) * 1024 + h * 64 + dt * 16 + hi * 4] = ov;
      uint2 ow2;
      ow2.x = cvtpk(accb[dt][0] * invb, accb[dt][1] * invb);
      ow2.y = cvtpk(accb[dt][2] * invb, accb[dt][3] * invb);
      *(uint2*)&O[((size_t)b * 2048 + qgb) * 1024 + h * 64 + dt * 16 + hi * 4] = ow2;
    }
  }
}

extern "C" void kernel_launch(void* const* d_in, const int* in_sizes, int n_in,
                              void* d_out, int out_size, void* d_ws, size_t ws_size,
                              hipStream_t stream) {
  const float* x  = (const float*)d_in[0];
  const float* qw = (const float*)d_in[1];
  const float* kw = (const float*)d_in[2];
  const float* vw = (const float*)d_in[3];
  const float* ow = (const float*)d_in[4];
  const int* pos  = (const int*)d_in[5];
  float* out = (float*)d_out;

  unsigned short* xb  = (unsigned short*)d_ws;            // [8192,1024]
  unsigned short* qwb = xb  + (size_t)8192 * 1024;        // [1024,1024] x4 (q|k|v|o)
  unsigned short* owb = qwb + (size_t)3 * 1024 * 1024;
  unsigned short* Qr  = owb + (size_t)1024 * 1024;        // [BH,S,DK], pre-scaled
  unsigned short* Kr  = Qr  + (size_t)8192 * 1024;        // [BH,S,DK]
  unsigned short* Vtr = Kr  + (size_t)8192 * 1024;        // [BH,DK,S]
  unsigned short* AO  = Vtr + (size_t)8192 * 1024;        // [8192,1024]
  float2* tab = (float2*)(AO + (size_t)8192 * 1024);      // [8192][32] cos/sin
  (void)Kr; (void)Vtr;

  cvt_all<<<7168, 256, 0, stream>>>(x, qw, kw, vw, ow, xb, pos, tab);

  dim3 gqkv(8, 128, 3);
  gemm_qkv<<<gqkv, 256, 0, stream>>>(xb, qwb, Qr, tab);
  attn_fwd<<<512, 256, 0, stream>>>(Qr, Kr, Vtr, AO);
  dim3 go(8, 128);
  gemm_o<<<go, 256, 0, stream>>>(AO, owb, out);
}

// Round 17
// 157.391 us; speedup vs baseline: 1.1445x; 1.1040x over previous
//
#include <hip/hip_runtime.h>
#include <hip/hip_bf16.h>

using bf16x8 = __attribute__((ext_vector_type(8))) short;
using f32x4  = __attribute__((ext_vector_type(4))) float;

#define MFMA_BF16(a, b, c) __builtin_amdgcn_mfma_f32_16x16x32_bf16((a), (b), (c), 0, 0, 0)

__device__ __forceinline__ unsigned short f2bf(float x) {
  union { float f; unsigned int u; } v; v.f = x;
  unsigned int r = v.u + 0x7fffu + ((v.u >> 16) & 1u);
  return (unsigned short)(r >> 16);
}

__device__ __forceinline__ unsigned int cvtpk(float a, float b) {
  __hip_bfloat162 h = __float22bfloat162_rn(make_float2(a, b));
  unsigned int u; __builtin_memcpy(&u, &h, 4); return u;
}

// truncate-pack two f32 -> bf16x2 (low = a). P>0 and the ones-MFMA denominator
// sums the same truncated values, so the bias cancels in the softmax ratio.
__device__ __forceinline__ unsigned int pack_trunc(float a, float b) {
  unsigned int ua, ub;
  __builtin_memcpy(&ua, &a, 4);
  __builtin_memcpy(&ub, &b, 4);
  return (ua >> 16) | (ub & 0xFFFF0000u);
}

// raw v_exp_f32 (no OCML range-fixup; exp2(-1e30)=0 natively)
__device__ __forceinline__ float fast_exp2(float x) {
#if __has_builtin(__builtin_amdgcn_exp2f)
  return __builtin_amdgcn_exp2f(x);
#else
  return exp2f(x);
#endif
}

__device__ __forceinline__ void gload16(const void* g, void* l) {
  __builtin_amdgcn_global_load_lds(
      (const __attribute__((address_space(1))) unsigned int*)g,
      (__attribute__((address_space(3))) unsigned int*)l, 16, 0, 0);
}

__device__ __forceinline__ void wait_and_barrier() {
  asm volatile("s_waitcnt vmcnt(0)" ::: "memory");
  __builtin_amdgcn_sched_barrier(0);
  __builtin_amdgcn_s_barrier();
  __builtin_amdgcn_sched_barrier(0);
}

// ---------------- f32 -> bf16 convert (all 5 inputs) + RoPE table, one launch ----------------
__global__ __launch_bounds__(256) void cvt_all(const float* __restrict__ x,
                                               const float* __restrict__ qw,
                                               const float* __restrict__ kw,
                                               const float* __restrict__ vw,
                                               const float* __restrict__ ow,
                                               unsigned short* __restrict__ out,
                                               const int* __restrict__ pos,
                                               float2* __restrict__ tab) {
  const int bid = blockIdx.x;
  if (bid >= 6144) {  // RoPE table segment: rows (bid-6144)*8 .. +7
    const int row = (bid - 6144) * 8 + (threadIdx.x >> 5);
    const int i = threadIdx.x & 31;
    const float p = (float)pos[row];
    const float invf = exp2f((float)(2 * i) * (-13.287712379549609f / 64.0f));
    float sn, cs;
    sincosf(p * invf, &sn, &cs);
    tab[(size_t)row * 32 + i] = make_float2(cs, sn);
    return;
  }
  int seg, loc;
  if (bid < 4096) { seg = 0; loc = bid; }
  else { seg = 1 + ((bid - 4096) >> 9); loc = (bid - 4096) & 511; }
  const float* srcs[5] = {x, qw, kw, vw, ow};
  const float* in = srcs[seg];
  const size_t obase = (seg == 0) ? 0 : ((size_t)8192 + (size_t)(seg - 1) * 1024) * 1024;
  const int i = loc * 2048 + threadIdx.x * 8;
  float4 f0 = *(const float4*)(in + i);
  float4 f1 = *(const float4*)(in + i + 4);
  bf16x8 o;
  o[0] = (short)f2bf(f0.x); o[1] = (short)f2bf(f0.y);
  o[2] = (short)f2bf(f0.z); o[3] = (short)f2bf(f0.w);
  o[4] = (short)f2bf(f1.x); o[5] = (short)f2bf(f1.y);
  o[6] = (short)f2bf(f1.z); o[7] = (short)f2bf(f1.w);
  *(bf16x8*)(out + obase + i) = o;
}

// ---------------- 128x128 BT-GEMM: C[m][n] = sum_k A[m][k] * Bw[n][k] ----------------
// Wave tile 64x64 (acc[4][4]) -> 512 B LDS per MFMA (vs 768 at 32x64).
// Staging: linear LDS [128][32] per operand with 2-way-conflict XOR swizzle
// applied on the GLOBAL source (rule #21: gload_lds dest must stay linear):
// logical chunk c of row r lives at physical chunk c ^ (r&3) ^ ((r>>2)&3).
// Read side folds to hi ^ (lrow&3) ^ ((lrow>>2)&3), invariant in mi/wr.
// Proven dbuf protocol: one wait_and_barrier per K-step, stage(t+1) after it.
// MODE 0: fused QKV (z: 0=Q RoPE+scale, 1=K RoPE, 2=V transposed), bf16 out
// MODE 2: f32 out [M,1024] (final projection)
template <int MODE>
__global__ __launch_bounds__(256) void gemm128(const unsigned short* __restrict__ A,
                                               const unsigned short* __restrict__ W,
                                               void* __restrict__ outp,
                                               const float2* __restrict__ tab) {
  constexpr int K = 1024;
  constexpr float SCALE = 0.18033688011112042f;  // 0.125 * log2(e)
  constexpr int SMEM_ELEMS = (MODE == 0) ? 17408 : 16384;  // epi C-tile vs staging
  __shared__ __align__(16) unsigned short smem[SMEM_ELEMS];
  const int tid  = threadIdx.x;
  const int lane = tid & 63, wave = tid >> 6;
  const int wr = wave >> 1, wc = wave & 1;           // wave tile 64x64 in 2x2
  const int z = (MODE == 0) ? blockIdx.z : 0;
  const unsigned short* Bw = W + (size_t)z * 1048576;
  // XCD-aware bijective remap: same-A-panel (row) blocks -> same XCD L2
  const int bid = blockIdx.x + (blockIdx.y << 3);    // [0,512)
  const int xcd = bid & 7;
  const int t6  = bid >> 3;                          // [0,64)
  const int bn0 = (t6 & 7) * 128;
  const int bm0 = (((t6 >> 3) << 3) + xcd) * 128;
  const int lrow = lane & 15, hi = lane >> 4;
  // staging: thread stages physical chunk (row=tid>>2, p=tid&3) of a 64-row
  // half; fetch logical chunk p ^ (row&3) ^ ((row>>2)&3) from global
  const int srow = tid >> 2;
  const int scol = ((tid & 3) ^ (srow & 3) ^ ((srow >> 2) & 3)) * 8;
  const unsigned short* gA = A + (size_t)(bm0 + srow) * K + scol;
  const unsigned short* gB = Bw + (size_t)(bn0 + srow) * K + scol;
  const int sw2 = (lrow & 3) ^ ((lrow >> 2) & 3);    // read-side swizzle
  const f32x4 z4 = {0.f, 0.f, 0.f, 0.f};
  f32x4 acc[4][4];
#pragma unroll
  for (int i = 0; i < 4; ++i)
#pragma unroll
    for (int j = 0; j < 4; ++j) acc[i][j] = z4;

  auto stage = [&](int k0, int c) {
    char* base = (char*)smem + c * 16384;
    gload16(gA + k0,                 base +         wave * 1024);   // A rows 0..63
    gload16(gA + k0 + (size_t)64 * K, base + 4096 + wave * 1024);   // A rows 64..127
    gload16(gB + k0,                 base + 8192 + wave * 1024);    // B rows 0..63
    gload16(gB + k0 + (size_t)64 * K, base + 12288 + wave * 1024);  // B rows 64..127
  };

  stage(0, 0);
  int cur = 0;
#pragma unroll 1
  for (int k0 = 0; k0 < K; k0 += 32) {
    wait_and_barrier();                  // tile k0 visible; prev buf reads done
    if (k0 + 32 < K) stage(k0 + 32, cur ^ 1);
    const char* ub = (const char*)smem + cur * 16384;
    bf16x8 af[4], bfr[4];
#pragma unroll
    for (int mi = 0; mi < 4; ++mi)
      af[mi] = *(const bf16x8*)(ub + (wr * 64 + mi * 16 + lrow) * 64 + ((hi ^ sw2) * 16));
#pragma unroll
    for (int ni = 0; ni < 4; ++ni)
      bfr[ni] = *(const bf16x8*)(ub + 8192 + (wc * 64 + ni * 16 + lrow) * 64 + ((hi ^ sw2) * 16));
#pragma unroll
    for (int mi = 0; mi < 4; ++mi)
#pragma unroll
      for (int ni = 0; ni < 4; ++ni)
        acc[mi][ni] = MFMA_BF16(af[mi], bfr[ni], acc[mi][ni]);
    cur ^= 1;
  }

  if (MODE == 2) {
#pragma unroll
    for (int mi = 0; mi < 4; ++mi)
#pragma unroll
      for (int r = 0; r < 4; ++r) {
        const int row = bm0 + wr * 64 + mi * 16 + hi * 4 + r;
#pragma unroll
        for (int ni = 0; ni < 4; ++ni) {
          const int col = bn0 + wc * 64 + ni * 16 + lrow;
          ((float*)outp)[(size_t)row * 1024 + col] = acc[mi][ni][r];
        }
      }
    return;
  }

  const int h0 = bn0 >> 6;                 // first of 2 heads in this 128-col tile
  const int bb = bm0 >> 11, s0 = bm0 & 2047;
  unsigned short* Qr = (unsigned short*)outp;
  unsigned short* dst = (z == 0) ? Qr : (z == 1 ? Qr + (size_t)8388608
                                                : Qr + (size_t)16777216);
  const float oscale = (z == 0) ? SCALE : 1.0f;
  __syncthreads();  // all waves done reading staging; reuse smem as C-tile
  if (z < 2) {
    // RoPE in registers (pair partner in lane^1), C-tile [128 s][136 pad]
#pragma unroll
    for (int mi = 0; mi < 4; ++mi)
#pragma unroll
      for (int ni = 0; ni < 4; ++ni) {
        const int col = wc * 64 + ni * 16 + lrow;
        const int d = col & 63;
#pragma unroll
        for (int r = 0; r < 4; ++r) {
          const int row = wr * 64 + mi * 16 + hi * 4 + r;
          const float2 t = tab[(size_t)(bm0 + row) * 32 + (d >> 1)];
          const float v = acc[mi][ni][r];
          const float other = __shfl_xor(v, 1);
          const float rv = (d & 1) ? (other * t.y + v * t.x) : (v * t.x - other * t.y);
          smem[row * 136 + col] = f2bf(rv * oscale);
        }
      }
    __syncthreads();
    // writeout: 2 heads x 128 rows x 8 chunks(16B) = 2048 chunks, 8 rounds
#pragma unroll
    for (int it = 0; it < 8; ++it) {
      const int c = it * 256 + tid;
      const int hl = c >> 10, rem = c & 1023;
      const int sl = rem >> 3, ch = (rem & 7) * 8;
      const bf16x8 val = *(const bf16x8*)&smem[sl * 136 + hl * 64 + ch];
      *(bf16x8*)&dst[((size_t)(bb * 16 + h0 + hl) * 2048 + s0 + sl) * 64 + ch] = val;
    }
  } else {
    // V: C^T tile [128 c][136 pad s] (transpose at LDS-write, packed r-quad)
#pragma unroll
    for (int mi = 0; mi < 4; ++mi)
#pragma unroll
      for (int ni = 0; ni < 4; ++ni) {
        const int col = wc * 64 + ni * 16 + lrow;
        ushort4 pk;
        pk.x = f2bf(acc[mi][ni][0]); pk.y = f2bf(acc[mi][ni][1]);
        pk.z = f2bf(acc[mi][ni][2]); pk.w = f2bf(acc[mi][ni][3]);
        *(ushort4*)&smem[col * 136 + wr * 64 + mi * 16 + hi * 4] = pk;
      }
    __syncthreads();
    // writeout: 128 cols x 16 chunks(16B of s) = 2048 chunks, 8 rounds
#pragma unroll
    for (int it = 0; it < 8; ++it) {
      const int c = it * 256 + tid;
      const int cl = c >> 4, sc = (c & 15) * 8;
      const bf16x8 val = *(const bf16x8*)&smem[cl * 136 + sc];
      *(bf16x8*)&dst[((size_t)(bb * 16 + h0 + (cl >> 6)) * 64 + (cl & 63)) * 2048 + s0 + sc] = val;
    }
  }
}

// ---------------- causal flash attention (swapped QK^T, no-max softmax) ----------------
// ROUND-14/16 PROVEN VERSION (62 us): QBLK=128, 2 q-chains/wave, K/V frags
// shared between chains, grid 512 with complementary pairing (qb <-> 15-qb,
// 17 tiles per block). Sync: {sync, stage128, sync, compute} per 128-row tile.
__global__ __launch_bounds__(256) void attn_fwd(const unsigned short* __restrict__ Q,
                                                const unsigned short* __restrict__ Kk,
                                                const unsigned short* __restrict__ Vt,
                                                unsigned short* __restrict__ O) {
  __shared__ __align__(16) unsigned short Ks[8192];     // [128 kv][64 d] swizzled
  __shared__ __align__(16) unsigned short Vs[8192];     // [64 d][128 kv] swizzled
  __shared__ __align__(16) unsigned short Plds[4][16][64];  // chunk-XOR swizzled
  const int p = blockIdx.x;
  const int L = (p & 7) * 64 + (p >> 3);  // XCD swizzle: 8 heads/XCD (4MB K/V = L2)
  const int bh = L >> 3, pr = L & 7;
  const int tid = threadIdx.x;
  const int lane = tid & 63, wave = tid >> 6;
  const int lrow = lane & 15, hi = lane >> 4;
  const int l7 = lrow & 7;
  const unsigned short* Qb = Q + (size_t)bh * 2048 * 64;
  const unsigned short* Kb = Kk + (size_t)bh * 2048 * 64;
  const unsigned short* Vb = Vt + (size_t)bh * 64 * 2048;
  const int rK   = tid >> 3;                              // +32/pass
  const int colK = ((tid & 7) ^ ((tid >> 3) & 7)) * 8;
  const int rV   = tid >> 4;
  const int colV = ((tid & 8) | ((tid & 7) ^ ((tid >> 4) & 7))) * 8;
  const int b = bh >> 4, h = bh & 15;
  const f32x4 z = {0.f, 0.f, 0.f, 0.f};
  const short one = (short)0x3F80;  // bf16 1.0
  const bf16x8 ones = {one, one, one, one, one, one, one, one};
  const int qrl = wave * 16 + lrow;   // local q row within a chain (0..63)

  auto stage128 = [&](int kv0) {
#pragma unroll
    for (int pass = 0; pass < 4; ++pass)
      gload16(Kb + (size_t)(kv0 + rK + 32 * pass) * 64 + colK,
              (char*)Ks + pass * 4096 + wave * 1024);
#pragma unroll
    for (int pass = 0; pass < 4; ++pass)
      gload16(Vb + (size_t)(rV + 16 * pass) * 2048 + kv0 + colV,
              (char*)Vs + pass * 4096 + wave * 1024);
  };

  for (int half = 0; half < 2; ++half) {
    const int qb = half ? (15 - pr) : pr;   // 128-row q block index
    const int qga = qb * 128 + qrl;         // chain a global q row
    const int qgb = qga + 64;               // chain b global q row
    const bf16x8 qfa0 = *(const bf16x8*)(Qb + (size_t)qga * 64 + hi * 8);
    const bf16x8 qfa1 = *(const bf16x8*)(Qb + (size_t)qga * 64 + 32 + hi * 8);
    const bf16x8 qfb0 = *(const bf16x8*)(Qb + (size_t)qgb * 64 + hi * 8);
    const bf16x8 qfb1 = *(const bf16x8*)(Qb + (size_t)qgb * 64 + 32 + hi * 8);
    f32x4 acca[4] = {z, z, z, z}, accb[4] = {z, z, z, z};
    f32x4 acc_la = z, acc_lb = z;

    // softmax + PV for one chain on one 64-kv half (st consumed; vf shared)
    auto sm_pv = [&](f32x4* st, const bf16x8* vf, f32x4* acc, f32x4& acc_l,
                     bool dg) {
      if (dg) {
#pragma unroll
        for (int n = 0; n < 4; ++n)
#pragma unroll
          for (int r = 0; r < 4; ++r)
            if (n * 16 + hi * 4 + r > qrl) st[n][r] = -1e30f;
      }
      float pe[16];
#pragma unroll
      for (int n = 0; n < 4; ++n)
#pragma unroll
        for (int r = 0; r < 4; ++r) pe[n * 4 + r] = fast_exp2(st[n][r]);
#pragma unroll
      for (int n = 0; n < 4; ++n) {
        uint2 pk;
        pk.x = pack_trunc(pe[n * 4 + 0], pe[n * 4 + 1]);
        pk.y = pack_trunc(pe[n * 4 + 2], pe[n * 4 + 3]);
        const int eo = ((((n * 2 + (hi >> 1)) ^ l7) << 3) | ((hi & 1) << 2));
        *(uint2*)&Plds[wave][lrow][eo] = pk;
      }
      const bf16x8 pf0 = *(const bf16x8*)&Plds[wave][lrow][(hi ^ l7) << 3];
      const bf16x8 pf1 = *(const bf16x8*)&Plds[wave][lrow][((4 + hi) ^ l7) << 3];
      acc_l = MFMA_BF16(ones, pf0, acc_l);   // row-sum on the matrix pipe
      acc_l = MFMA_BF16(ones, pf1, acc_l);
#pragma unroll
      for (int dt = 0; dt < 4; ++dt) {
        acc[dt] = MFMA_BF16(vf[dt * 2], pf0, acc[dt]);
        acc[dt] = MFMA_BF16(vf[dt * 2 + 1], pf1, acc[dt]);
      }
    };

    // one 64-kv half: K/V frags read once, feed both chains
    auto process_half = [&](const char* Kbase, const char* Vbase,
                            bool doA, bool dgA, bool dgB) {
      bf16x8 kf[8];
#pragma unroll
      for (int n = 0; n < 4; ++n) {
        const int rk = n * 16 + lrow;
        kf[n * 2]     = *(const bf16x8*)(Kbase + rk * 128 + ((hi ^ l7) * 16));
        kf[n * 2 + 1] = *(const bf16x8*)(Kbase + rk * 128 + (((4 + hi) ^ l7) * 16));
      }
      f32x4 sta[4], stb[4];
      __builtin_amdgcn_s_setprio(1);
      if (doA) {
#pragma unroll
        for (int n = 0; n < 4; ++n) {
          sta[n] = MFMA_BF16(kf[n * 2], qfa0, z);
          sta[n] = MFMA_BF16(kf[n * 2 + 1], qfa1, sta[n]);
        }
      }
#pragma unroll
      for (int n = 0; n < 4; ++n) {
        stb[n] = MFMA_BF16(kf[n * 2], qfb0, z);
        stb[n] = MFMA_BF16(kf[n * 2 + 1], qfb1, stb[n]);
      }
      __builtin_amdgcn_s_setprio(0);
      bf16x8 vf[8];
#pragma unroll
      for (int dt = 0; dt < 4; ++dt) {
        const int rv = dt * 16 + lrow;
        vf[dt * 2]     = *(const bf16x8*)(Vbase + rv * 256 + ((hi ^ l7) * 16));
        vf[dt * 2 + 1] = *(const bf16x8*)(Vbase + rv * 256 + (((4 + hi) ^ l7) * 16));
      }
      if (doA) sm_pv(sta, vf, acca, acc_la, dgA);
      sm_pv(stb, vf, accb, acc_lb, dgB);
    };

#pragma unroll 1
    for (int f = 0; f <= qb; ++f) {
      __syncthreads();                     // prev tile's LDS reads done
      stage128(f * 128);
      __syncthreads();                     // staged tile visible
      const bool dg = (f == qb);
      process_half((char*)Ks, (char*)Vs, true, dg, false);             // kv 0..63
      process_half((char*)Ks + 8192, (char*)Vs + 128, !dg, false, dg); // kv 64..127
    }

    const float inva = 1.0f / acc_la[0];
    const float invb = 1.0f / acc_lb[0];
#pragma unroll
    for (int dt = 0; dt < 4; ++dt) {
      uint2 ov;
      ov.x = cvtpk(acca[dt][0] * inva, acca[dt][1] * inva);
      ov.y = cvtpk(acca[dt][2] * inva, acca[dt][3] * inva);
      *(uint2*)&O[((size_t)b * 2048 + qga) * 1024 + h * 64 + dt * 16 + hi * 4] = ov;
      uint2 ow2;
      ow2.x = cvtpk(accb[dt][0] * invb, accb[dt][1] * invb);
      ow2.y = cvtpk(accb[dt][2] * invb, accb[dt][3] * invb);
      *(uint2*)&O[((size_t)b * 2048 + qgb) * 1024 + h * 64 + dt * 16 + hi * 4] = ow2;
    }
  }
}

extern "C" void kernel_launch(void* const* d_in, const int* in_sizes, int n_in,
                              void* d_out, int out_size, void* d_ws, size_t ws_size,
                              hipStream_t stream) {
  const float* x  = (const float*)d_in[0];
  const float* qw = (const float*)d_in[1];
  const float* kw = (const float*)d_in[2];
  const float* vw = (const float*)d_in[3];
  const float* ow = (const float*)d_in[4];
  const int* pos  = (const int*)d_in[5];
  float* out = (float*)d_out;

  unsigned short* xb  = (unsigned short*)d_ws;            // [8192,1024]
  unsigned short* qwb = xb  + (size_t)8192 * 1024;        // [1024,1024] x4 (q|k|v|o)
  unsigned short* owb = qwb + (size_t)3 * 1024 * 1024;
  unsigned short* Qr  = owb + (size_t)1024 * 1024;        // [BH,S,DK], pre-scaled
  unsigned short* Kr  = Qr  + (size_t)8192 * 1024;        // [BH,S,DK]
  unsigned short* Vtr = Kr  + (size_t)8192 * 1024;        // [BH,DK,S]
  unsigned short* AO  = Vtr + (size_t)8192 * 1024;        // [8192,1024]
  float2* tab = (float2*)(AO + (size_t)8192 * 1024);      // [8192][32] cos/sin
  (void)Kr; (void)Vtr;

  cvt_all<<<7168, 256, 0, stream>>>(x, qw, kw, vw, ow, xb, pos, tab);

  dim3 gqkv(8, 64, 3);
  gemm128<0><<<gqkv, 256, 0, stream>>>(xb, qwb, Qr, tab);
  attn_fwd<<<512, 256, 0, stream>>>(Qr, Kr, Vtr, AO);
  dim3 go(8, 64);
  gemm128<2><<<go, 256, 0, stream>>>(AO, owb, out, nullptr);
}